// Round 6
// baseline (300.375 us; speedup 1.0000x reference)
//
#include <hip/hip_runtime.h>
#include <hip/hip_fp16.h>
#include <stdint.h>

// Problem constants: B=8, H=W=128, C=F=256, K=7, PAD=3, rs=128
typedef _Float16 half8 __attribute__((ext_vector_type(8)));   // 8 fp16 = 4 VGPR (MFMA A/B frag)
typedef _Float16 half2v __attribute__((ext_vector_type(2)));  // packed fp16 pair
typedef __attribute__((ext_vector_type(4))) float f32x4;      // MFMA C/D frag

__device__ __forceinline__ unsigned short f2h(float f) {      // RNE fp32->fp16
  __half h = __float2half(f);
  unsigned short u; __builtin_memcpy(&u, &h, 2); return u;
}
__device__ __forceinline__ unsigned pk2h(float a, float b) {  // RTZ packed pair (staging only)
  auto v = __builtin_amdgcn_cvt_pkrtz(a, b);
  unsigned u; __builtin_memcpy(&u, &v, 4); return u;
}
__device__ __forceinline__ half2v h2cast(unsigned u) {
  half2v v; __builtin_memcpy(&v, &u, 4); return v;
}

#if __has_builtin(__builtin_amdgcn_fdot2)
__device__ __forceinline__ float dot2(half2v a, half2v b, float c) {
  return __builtin_amdgcn_fdot2(a, b, c, false);
}
#else
__device__ __forceinline__ float dot2(half2v a, half2v b, float c) {
  return c + (float)a[0] * (float)b[0] + (float)a[1] * (float)b[1];
}
#endif

// async global->LDS, 16B per lane; lds dest = wave-uniform base + lane*16
__device__ __forceinline__ void gl_lds16(const void* g, void* l) {
  __builtin_amdgcn_global_load_lds(
      (const __attribute__((address_space(1))) void*)g,
      (__attribute__((address_space(3))) void*)l, 16, 0, 0);
}

// ---------------- Kernel 0: x fp32 -> fp16 (into d_out scratch region) ----------------
__global__ __launch_bounds__(256) void xcvt(const float* __restrict__ x,
                                            unsigned short* __restrict__ xh) {
  const size_t i = ((size_t)blockIdx.x * 256 + threadIdx.x) * 8;
  float4 a = *(const float4*)&x[i];
  float4 b = *(const float4*)&x[i + 4];
  uint4 o;
  o.x = pk2h(a.x, a.y); o.y = pk2h(a.z, a.w);
  o.z = pk2h(b.x, b.y); o.w = pk2h(b.z, b.w);
  *(uint4*)&xh[i] = o;
}

// ---------------- Kernel 1: weight transpose + fp32->fp16 ----------------
__global__ __launch_bounds__(256) void wconv(const float* __restrict__ Wq,
                                             const float* __restrict__ Wk,
                                             const float* __restrict__ Wv,
                                             unsigned short* __restrict__ Wb) {
  const int e = blockIdx.x;
  const int w = e >> 8;
  const int n = e & 255;
  const float* W = (w == 0) ? Wq : ((w == 1) ? Wk : Wv);
  const int k = threadIdx.x;
  Wb[(size_t)e * 256 + k] = f2h(W[(size_t)k * 256 + n]);
}

// ---------------- Kernel 2: fused QKV GEMM (fp16 MFMA, global_load_lds staging) ----------
__global__ __launch_bounds__(256) void qkv_gemm(const unsigned short* __restrict__ xh,
                                                const unsigned short* __restrict__ Wb,
                                                unsigned short* __restrict__ qkv) {
  __shared__ unsigned char ldsb[32768];

  const int tid = threadIdx.x;
  const int l = tid & 63, l15 = l & 15, l4 = l >> 4;
  const int wv = tid >> 6, wr = wv >> 1, wc = wv & 1;

  // XCD-aware chunked swizzle: 6144 blocks, 8 XCDs, 768 per XCD (bijective).
  const int pid = blockIdx.x;
  const int cid = (pid & 7) * 768 + (pid >> 3);
  const int by = cid / 6;
  const int bx = cid - by * 6;
  const size_t row0 = (size_t)by * 128;
  const int n0 = bx * 128;

  const int rbase0 = wv * 32, rbase1 = wv * 32 + 16;
  const int rA0 = rbase0 + (l >> 2), rA1 = rbase1 + (l >> 2);
  const int q0 = (l & 3) ^ ((rA0 >> 1) & 3), q1 = (l & 3) ^ ((rA1 >> 1) & 3);
  const unsigned short* gA0 = xh + (row0 + rA0) * 256 + q0 * 8;
  const unsigned short* gA1 = xh + (row0 + rA1) * 256 + q1 * 8;
  const unsigned short* gB0 = Wb + (size_t)(n0 + rA0) * 256 + q0 * 8;
  const unsigned short* gB1 = Wb + (size_t)(n0 + rA1) * 256 + q1 * 8;

  f32x4 acc[4][4] = {};

  auto stage = [&](int s, int d) {
    gl_lds16(gA0 + s * 32, &ldsb[d * 8192 + rbase0 * 64]);
    gl_lds16(gA1 + s * 32, &ldsb[d * 8192 + rbase1 * 64]);
    gl_lds16(gB0 + s * 32, &ldsb[16384 + d * 8192 + rbase0 * 64]);
    gl_lds16(gB1 + s * 32, &ldsb[16384 + d * 8192 + rbase1 * 64]);
  };

  stage(0, 0);
  __syncthreads();

  for (int s = 0; s < 8; ++s) {
    const int d = s & 1;
    if (s < 7) stage(s + 1, d ^ 1);
    half8 af[4], bf[4];
#pragma unroll
    for (int m = 0; m < 4; ++m) {
      const int r = wr * 64 + m * 16 + l15;
      af[m] = *(const half8*)&ldsb[d * 8192 + r * 64 + ((l4 ^ ((r >> 1) & 3)) * 16)];
    }
#pragma unroll
    for (int n = 0; n < 4; ++n) {
      const int r = wc * 64 + n * 16 + l15;
      bf[n] = *(const half8*)&ldsb[16384 + d * 8192 + r * 64 + ((l4 ^ ((r >> 1) & 3)) * 16)];
    }
#pragma unroll
    for (int n = 0; n < 4; ++n)
#pragma unroll
      for (int m = 0; m < 4; ++m)
        acc[m][n] = __builtin_amdgcn_mfma_f32_16x16x32_f16(af[m], bf[n], acc[m][n], 0, 0, 0);
    __syncthreads();
  }

  // Epilogue: C/D mapping col=lane&15, row=(lane>>4)*4+reg (m89-verified)
#pragma unroll
  for (int m = 0; m < 4; ++m)
#pragma unroll
    for (int n = 0; n < 4; ++n) {
      const int ng = n0 + wc * 64 + n * 16 + l15;
      unsigned short* op = qkv + (size_t)(ng >> 8) * 33554432 + (ng & 255);
#pragma unroll
      for (int r = 0; r < 4; ++r) {
        const size_t grow = row0 + wr * 64 + m * 16 + l4 * 4 + r;
        op[grow * 256] = f2h(acc[m][n][r]);
      }
    }
}

// ---------------- Kernel 2b: per-pixel relative-position projections ----------------
__global__ __launch_bounds__(256) void qrel(const unsigned short* __restrict__ q,
                                            const float* __restrict__ relx,
                                            const float* __restrict__ rely,
                                            unsigned short* __restrict__ qr) {
  __shared__ unsigned wpk[896];  // [0..447] x-pairs, [448..895] y-pairs; wpk[c2*7+j]
  for (int i = threadIdx.x; i < 896; i += 256) {
    const int hf = (i >= 448) ? 1 : 0;
    const int r = i - hf * 448;
    const int c2 = r / 7, j = r - c2 * 7;
    const float* R = hf ? rely : relx;
    wpk[i] = pk2h(R[(2 * c2) * 7 + j], R[(2 * c2 + 1) * 7 + j]);
  }
  __syncthreads();
  const size_t pix = (size_t)blockIdx.x * 256 + threadIdx.x;
  const uint4* qp = (const uint4*)(q + pix * 256);  // 32 uint4 = 256 fp16 channels
  float ax[7] = {0, 0, 0, 0, 0, 0, 0}, ay[7] = {0, 0, 0, 0, 0, 0, 0};
#pragma unroll
  for (int g = 0; g < 32; ++g) {
    const uint4 u = qp[g];
    const int c2b = (g & 15) * 4;
    if (g < 16) {
#pragma unroll
      for (int j = 0; j < 7; ++j) {
        float s = ax[j];
        s = dot2(h2cast(u.x), h2cast(wpk[(c2b + 0) * 7 + j]), s);
        s = dot2(h2cast(u.y), h2cast(wpk[(c2b + 1) * 7 + j]), s);
        s = dot2(h2cast(u.z), h2cast(wpk[(c2b + 2) * 7 + j]), s);
        s = dot2(h2cast(u.w), h2cast(wpk[(c2b + 3) * 7 + j]), s);
        ax[j] = s;
      }
    } else {
#pragma unroll
      for (int j = 0; j < 7; ++j) {
        float s = ay[j];
        s = dot2(h2cast(u.x), h2cast(wpk[448 + (c2b + 0) * 7 + j]), s);
        s = dot2(h2cast(u.y), h2cast(wpk[448 + (c2b + 1) * 7 + j]), s);
        s = dot2(h2cast(u.z), h2cast(wpk[448 + (c2b + 2) * 7 + j]), s);
        s = dot2(h2cast(u.w), h2cast(wpk[448 + (c2b + 3) * 7 + j]), s);
        ay[j] = s;
      }
    }
  }
  uint4 o0, o1;
  o0.x = pk2h(ax[0], ax[1]); o0.y = pk2h(ax[2], ax[3]);
  o0.z = pk2h(ax[4], ax[5]); o0.w = pk2h(ax[6], ay[0]);
  o1.x = pk2h(ay[1], ay[2]); o1.y = pk2h(ay[3], ay[4]);
  o1.z = pk2h(ay[5], ay[6]); o1.w = 0;
  uint4* dst = (uint4*)(qr + pix * 512);
  dst[0] = o0; dst[1] = o1;
}

// ---------------- Kernel 3: fused windowed attention ----------------
// v7: MFMA phase A. Six rounds of counters all showed MfmaUtil=0 while LDS-read+VALU
// bind (v3=167us best). Scores ARE GEMM-shaped: per wave, per 2x8 query group g,
// S[16q][112keys] = Q(16x32ch) @ K_union^T per chunk. Operand conventions copied from
// qkv_gemm (verified): A lane row=l&15 k=(l>>4)*8; B lane col=l&15 same k; D col=l&15
// (key), row=(lane>>4)*4+reg (query). B-frag = ONE ds_read_b128: plane (l>>4) holds
// exactly the frag's 8 ch; slot stride 16B keeps v3's conflict-free bank walk (wrap
// +25 slots ≡ +4 banks, same progression). A-frag = per-lane global 16B Q load.
// Per wave/chunk: 28 ds_read + 28 MFMA vs v3's 196 ds_read + 784 fdot2.
// acc f32x4[4g][7t] = 112 VGPR, statically indexed (v2/v5 spill lesson).
// Redistribution: valid-window scores (di,dj in [0,7)) written f32 to a P-buffer
// ALIASING the dead kv double-buffer (53KB <= 68KB, no occupancy cost); each thread
// loads its own sc[49]; relpos+softmax+phase B = v3 verbatim. V chunk-0 staging moved
// after the P hand-off; OOB halo slots re-zeroed before phase B.
__global__ __launch_bounds__(256) void attn(const unsigned short* __restrict__ qkv,
                                            const float* __restrict__ bias,
                                            const unsigned short* __restrict__ qrelb,
                                            float* __restrict__ out) {
  __shared__ unsigned short kv[2][4][4256];  // 2 buf x 4 planes x 532 slots*8 = 68096 B

  const int tid = threadIdx.x;
  const int col = tid & 31, row = tid >> 5;
  const int wv = tid >> 6;                       // wave 0..3 (owns rows 2wv, 2wv+1)
  const int l = tid & 63, lo = l & 15, hi = l >> 4;

  const int pid = blockIdx.x;
  const int cid = (pid & 7) * 64 + (pid >> 3);   // XCD-chunked (512 = 8*64, bijective)
  const int ht = cid & 15, wt = (cid >> 4) & 3, b = cid >> 6;

  const int h = ht * 8 + row, w = wt * 32 + col;
  const size_t pix = (size_t)((b * 128 + h) * 128 + w);
  const int pbase = row * 38 + col;              // this thread's halo-pixel index

  const unsigned short* qb = qkv;
  const unsigned short* kb = qkv + 33554432;
  const unsigned short* vb = qkv + 67108864;

  // staging geometry: thread covers halo px tid, tid+256, tid+512 (532 total)
  const int pr0 = tid / 38, pc0 = tid - pr0 * 38;
  const int gh0 = ht * 8 + pr0 - 3, gw0 = wt * 32 + pc0 - 3;
  const bool ok0 = ((unsigned)gh0 < 128u) && ((unsigned)gw0 < 128u);
  const long long go0 = ((long long)((b * 128 + gh0) * 128 + gw0)) * 256;  // shorts

  const int p1 = tid + 256;
  const int pr1 = p1 / 38, pc1 = p1 - pr1 * 38;
  const int gh1 = ht * 8 + pr1 - 3, gw1 = wt * 32 + pc1 - 3;
  const bool ok1 = ((unsigned)gh1 < 128u) && ((unsigned)gw1 < 128u);
  const long long go1 = ((long long)((b * 128 + gh1) * 128 + gw1)) * 256;

  const int p2 = tid + 512;
  const int pr2 = p2 / 38, pc2 = p2 - pr2 * 38;
  const int gh2 = ht * 8 + pr2 - 3, gw2 = wt * 32 + pc2 - 3;
  const bool ok2 = (p2 < 532) && ((unsigned)gh2 < 128u) && ((unsigned)gw2 < 128u);
  const long long go2 = ((long long)((b * 128 + gh2) * 128 + gw2)) * 256;

  const int wb8 = wv * 512;  // wave's pixel-group base * 8 shorts

  // async stage of chunk c (4 planes) into buffer d (no registers, no waits)
  auto stage = [&](const unsigned short* base, int c, int d) {
#pragma unroll
    for (int g = 0; g < 4; ++g) {
      if (ok0) gl_lds16(base + go0 + c * 32 + g * 8, &kv[d][g][wb8]);
      if (ok1) gl_lds16(base + go1 + c * 32 + g * 8, &kv[d][g][2048 + wb8]);
      if (ok2) gl_lds16(base + go2 + c * 32 + g * 8, &kv[d][g][4096]);
    }
  };

  // zero OOB halo slots (both buffers). Needed twice: before phase A, and again after
  // the P-buffer phase clobbers kv.
  auto zero_oob = [&]() {
    const uint4 z = make_uint4(0u, 0u, 0u, 0u);
    for (int p = tid; p < 532; p += 256) {
      const int pr = p / 38, pc = p - pr * 38;
      const int gh = ht * 8 + pr - 3, gw = wt * 32 + pc - 3;
      if (!((unsigned)gh < 128u && (unsigned)gw < 128u)) {
#pragma unroll
        for (int d = 0; d < 2; ++d)
#pragma unroll
          for (int g = 0; g < 4; ++g)
            *(uint4*)&kv[d][g][p * 8] = z;
      }
    }
  };

  zero_oob();
  stage(kb, 0, 0);
  __syncthreads();   // implicit vmcnt(0): chunk-0 K staged + OOB zeros visible

  // ---- Phase A (MFMA): per group g (query cols 8g..8g+7, rows 2wv..2wv+1),
  //      acc[g][t] accumulates S[16q][16keys of tile t] over 8 channel chunks.
  // union cell (ur,uc) in 8x14: p = 16t+lo -> ur=p/14, uc=p%14;
  // halo slot (g=0) = (2wv+ur)*38 + uc; group g adds 8 slots.
  int slot0[7];
#pragma unroll
  for (int t = 0; t < 7; ++t) {
    const int p = t * 16 + lo;
    const int ur = p / 14, uc = p - ur * 14;
    slot0[t] = (2 * wv + ur) * 38 + uc;
  }
  // lane's query pixel for g=0: qq = lo -> (qr,qc) = (lo>>3, lo&7)
  const size_t qpix = (size_t)((b * 128 + ht * 8 + 2 * wv + (lo >> 3)) * 128 + wt * 32 + (lo & 7));
  const unsigned short* qlane = qb + qpix * 256 + hi * 8;

  f32x4 acc[4][7] = {};

  for (int s = 0; s < 8; ++s) {
    const int d = s & 1;
    if (s < 7) stage(kb, s + 1, d ^ 1);
    half8 qf[4];
#pragma unroll
    for (int g = 0; g < 4; ++g)
      qf[g] = *(const half8*)(qlane + (size_t)g * 2048 + s * 32);
    const unsigned short* kpl = &kv[d][hi][0];
    __builtin_amdgcn_s_setprio(1);
#pragma unroll
    for (int t = 0; t < 7; ++t) {
      const unsigned short* kt = kpl + slot0[t] * 8;
#pragma unroll
      for (int g = 0; g < 4; ++g) {
        const half8 kf = *(const half8*)(kt + g * 64);
        acc[g][t] = __builtin_amdgcn_mfma_f32_16x16x32_f16(qf[g], kf, acc[g][t], 0, 0, 0);
      }
    }
    __builtin_amdgcn_s_setprio(0);
    __syncthreads();
  }

  // ---- P hand-off: scatter valid-window scores (f32) into P-buffer aliasing kv.
  // Writer lane holds, per (t,r): query qq=hi*4+r (row (lane>>4)*4+reg), key p=16t+lo
  // (col l&15). valid iff di=ur-(qq>>3), dj=uc-(qq&7) in [0,7). P row = phase-B tid of
  // the query pixel = wv*64 + qr*32 + 8g + qc; row stride 52 floats (208 B).
  float* pbuf = (float*)&kv[0][0][0];  // 256 rows x 52 f32 = 53248 B <= 68096 B
#pragma unroll
  for (int t = 0; t < 7; ++t) {
    const int p = t * 16 + lo;
    const int ur = p / 14, uc = p - ur * 14;
#pragma unroll
    for (int r = 0; r < 4; ++r) {
      const int qq = hi * 4 + r;
      const int di = ur - (qq >> 3), dj = uc - (qq & 7);
      if (((unsigned)di < 7u) && ((unsigned)dj < 7u)) {
        const int prow_ = wv * 64 + (qq >> 3) * 32 + (qq & 7);
        const int pslot = di * 7 + dj;
#pragma unroll
        for (int g = 0; g < 4; ++g)
          pbuf[(prow_ + g * 8) * 52 + pslot] = acc[g][t][r];
      }
    }
  }
  __syncthreads();

  // each thread loads its own 49 scores
  float sc[49];
  {
    const float* prow = pbuf + tid * 52;
#pragma unroll
    for (int k = 0; k < 12; ++k) {
      const float4 v = ((const float4*)prow)[k];
      sc[k * 4 + 0] = v.x; sc[k * 4 + 1] = v.y;
      sc[k * 4 + 2] = v.z; sc[k * 4 + 3] = v.w;
    }
    sc[48] = prow[48];
  }
  __syncthreads();   // all P reads done before kv is clobbered below

  // restore kv for phase B: re-zero OOB slots, stage V chunk 0 into buf 0
  zero_oob();
  stage(vb, 0, 0);

  // qrel: 14 fp16 at this pixel's out-slot head (written by qrel; we overwrite later)
  float qx[7], qy[7];
  {
    const uint4* rp = (const uint4*)(qrelb + pix * 512);
    uint4 r0 = rp[0], r1 = rp[1];
    half2v a0 = h2cast(r0.x), a1 = h2cast(r0.y), a2 = h2cast(r0.z), a3 = h2cast(r0.w);
    half2v b0 = h2cast(r1.x), b1 = h2cast(r1.y), b2 = h2cast(r1.z);
    qx[0] = a0[0]; qx[1] = a0[1]; qx[2] = a1[0]; qx[3] = a1[1];
    qx[4] = a2[0]; qx[5] = a2[1]; qx[6] = a3[0];
    qy[0] = a3[1]; qy[1] = b0[0]; qy[2] = b0[1]; qy[3] = b1[0];
    qy[4] = b1[1]; qy[5] = b2[0]; qy[6] = b2[1];
  }

  // ---- softmax over 49 (fp32, per thread) — v3 verbatim ----
#pragma unroll
  for (int i = 0; i < 7; ++i)
#pragma unroll
    for (int j = 0; j < 7; ++j) sc[i * 7 + j] += qx[j] + qy[i];
  float mx = sc[0];
#pragma unroll
  for (int t = 1; t < 49; ++t) mx = fmaxf(mx, sc[t]);
  float sum = 0.0f;
#pragma unroll
  for (int t = 0; t < 49; ++t) {
    float e = __expf(sc[t] - mx);
    sc[t] = e;
    sum += e;
  }
  const float invs = 1.0f / sum;
  unsigned pw[49];
#pragma unroll
  for (int t = 0; t < 49; ++t) {
    const unsigned short ph = f2h(sc[t] * invs);
    pw[t] = (unsigned)ph | ((unsigned)ph << 16);
  }
  __syncthreads();   // vmcnt(0): V chunk 0 + re-zeroed OOB visible

  // ---- Phase B: out = sum p*v + bias — v3 verbatim ----
  for (int s = 0; s < 8; ++s) {
    const int d = s & 1;
    const int f0 = s * 32;
    if (s < 7) stage(vb, s + 1, d ^ 1);
    half2v acc2[16];
#pragma unroll
    for (int a = 0; a < 16; ++a) acc2[a] = half2v{(_Float16)0, (_Float16)0};
    __builtin_amdgcn_s_setprio(1);
#pragma unroll
    for (int i = 0; i < 7; ++i)
#pragma unroll
      for (int j = 0; j < 7; ++j) {
        const int q8 = (pbase + i * 38 + j) * 8;
        uint4 v0 = *(const uint4*)&kv[d][0][q8];
        uint4 v1 = *(const uint4*)&kv[d][1][q8];
        uint4 v2 = *(const uint4*)&kv[d][2][q8];
        uint4 v3 = *(const uint4*)&kv[d][3][q8];
        const half2v p2h = h2cast(pw[i * 7 + j]);
        acc2[0] += p2h * h2cast(v0.x);  acc2[1] += p2h * h2cast(v0.y);
        acc2[2] += p2h * h2cast(v0.z);  acc2[3] += p2h * h2cast(v0.w);
        acc2[4] += p2h * h2cast(v1.x);  acc2[5] += p2h * h2cast(v1.y);
        acc2[6] += p2h * h2cast(v1.z);  acc2[7] += p2h * h2cast(v1.w);
        acc2[8] += p2h * h2cast(v2.x);  acc2[9] += p2h * h2cast(v2.y);
        acc2[10] += p2h * h2cast(v2.z); acc2[11] += p2h * h2cast(v2.w);
        acc2[12] += p2h * h2cast(v3.x); acc2[13] += p2h * h2cast(v3.y);
        acc2[14] += p2h * h2cast(v3.z); acc2[15] += p2h * h2cast(v3.w);
      }
    __builtin_amdgcn_s_setprio(0);
#pragma unroll
    for (int fq = 0; fq < 8; ++fq) {
      float4 bv = *(const float4*)&bias[f0 + fq * 4];
      float4 o;
      o.x = (float)acc2[fq * 2 + 0][0] + bv.x;
      o.y = (float)acc2[fq * 2 + 0][1] + bv.y;
      o.z = (float)acc2[fq * 2 + 1][0] + bv.z;
      o.w = (float)acc2[fq * 2 + 1][1] + bv.w;
      *(float4*)&out[pix * 256 + f0 + fq * 4] = o;
    }
    if (s < 7) __syncthreads();
  }
}

extern "C" void kernel_launch(void* const* d_in, const int* in_sizes, int n_in,
                              void* d_out, int out_size, void* d_ws, size_t ws_size,
                              hipStream_t stream) {
  const float* x = (const float*)d_in[0];
  const float* Wq = (const float*)d_in[1];
  const float* Wk = (const float*)d_in[2];
  const float* Wv = (const float*)d_in[3];
  const float* relx = (const float*)d_in[4];
  const float* rely = (const float*)d_in[5];
  const float* bias = (const float*)d_in[6];
  float* out = (float*)d_out;

  // d_out doubles as scratch: xh (fp16 x) dead after qkv_gemm; qrel writes 32 B into each
  // pixel's out slot head, read by attn before that slot is overwritten.
  unsigned short* xh = (unsigned short*)d_out;
  unsigned short* qrl = (unsigned short*)d_out;
  // ws layout: Wb (fp16, 768*256 = 384 KB) | qkv (3 * 33554432 fp16 = 192 MB)
  unsigned short* Wb = (unsigned short*)d_ws;
  unsigned short* qkv = (unsigned short*)((char*)d_ws + 393216);

  xcvt<<<dim3(16384), dim3(256), 0, stream>>>(x, xh);
  wconv<<<dim3(768), dim3(256), 0, stream>>>(Wq, Wk, Wv, Wb);
  qkv_gemm<<<dim3(6144), dim3(256), 0, stream>>>(xh, Wb, qkv);
  qrel<<<dim3(512), dim3(256), 0, stream>>>(qkv, relx, rely, qrl);
  attn<<<dim3(512), dim3(256), 0, stream>>>(qkv, bias, qrl, out);
}

// Round 7
// 282.720 us; speedup vs baseline: 1.0624x; 1.0624x over previous
//
#include <hip/hip_runtime.h>
#include <hip/hip_fp16.h>
#include <stdint.h>

// Problem constants: B=8, H=W=128, C=F=256, K=7, PAD=3, rs=128
typedef _Float16 half8 __attribute__((ext_vector_type(8)));   // 8 fp16 = 4 VGPR (MFMA A/B frag)
typedef _Float16 half2v __attribute__((ext_vector_type(2)));  // packed fp16 pair
typedef __attribute__((ext_vector_type(4))) float f32x4;      // MFMA C/D frag

__device__ __forceinline__ unsigned short f2h(float f) {      // RNE fp32->fp16
  __half h = __float2half(f);
  unsigned short u; __builtin_memcpy(&u, &h, 2); return u;
}
__device__ __forceinline__ unsigned pk2h(float a, float b) {  // RTZ packed pair (staging only)
  auto v = __builtin_amdgcn_cvt_pkrtz(a, b);
  unsigned u; __builtin_memcpy(&u, &v, 4); return u;
}
__device__ __forceinline__ half2v h2cast(unsigned u) {
  half2v v; __builtin_memcpy(&v, &u, 4); return v;
}

#if __has_builtin(__builtin_amdgcn_fdot2)
__device__ __forceinline__ float dot2(half2v a, half2v b, float c) {
  return __builtin_amdgcn_fdot2(a, b, c, false);
}
#else
__device__ __forceinline__ float dot2(half2v a, half2v b, float c) {
  return c + (float)a[0] * (float)b[0] + (float)a[1] * (float)b[1];
}
#endif

// async global->LDS, 16B per lane; lds dest = wave-uniform base + lane*16
__device__ __forceinline__ void gl_lds16(const void* g, void* l) {
  __builtin_amdgcn_global_load_lds(
      (const __attribute__((address_space(1))) void*)g,
      (__attribute__((address_space(3))) void*)l, 16, 0, 0);
}

// ---------------- Kernel 0: x fp32 -> fp16 (into d_out scratch region) ----------------
__global__ __launch_bounds__(256) void xcvt(const float* __restrict__ x,
                                            unsigned short* __restrict__ xh) {
  const size_t i = ((size_t)blockIdx.x * 256 + threadIdx.x) * 8;
  float4 a = *(const float4*)&x[i];
  float4 b = *(const float4*)&x[i + 4];
  uint4 o;
  o.x = pk2h(a.x, a.y); o.y = pk2h(a.z, a.w);
  o.z = pk2h(b.x, b.y); o.w = pk2h(b.z, b.w);
  *(uint4*)&xh[i] = o;
}

// ---------------- Kernel 1: weight transpose + fp32->fp16 ----------------
__global__ __launch_bounds__(256) void wconv(const float* __restrict__ Wq,
                                             const float* __restrict__ Wk,
                                             const float* __restrict__ Wv,
                                             unsigned short* __restrict__ Wb) {
  const int e = blockIdx.x;
  const int w = e >> 8;
  const int n = e & 255;
  const float* W = (w == 0) ? Wq : ((w == 1) ? Wk : Wv);
  const int k = threadIdx.x;
  Wb[(size_t)e * 256 + k] = f2h(W[(size_t)k * 256 + n]);
}

// ---------------- Kernel 2: fused QKV GEMM (fp16 MFMA, global_load_lds staging) ----------
__global__ __launch_bounds__(256) void qkv_gemm(const unsigned short* __restrict__ xh,
                                                const unsigned short* __restrict__ Wb,
                                                unsigned short* __restrict__ qkv) {
  __shared__ unsigned char ldsb[32768];

  const int tid = threadIdx.x;
  const int l = tid & 63, l15 = l & 15, l4 = l >> 4;
  const int wv = tid >> 6, wr = wv >> 1, wc = wv & 1;

  // XCD-aware chunked swizzle: 6144 blocks, 8 XCDs, 768 per XCD (bijective).
  const int pid = blockIdx.x;
  const int cid = (pid & 7) * 768 + (pid >> 3);
  const int by = cid / 6;
  const int bx = cid - by * 6;
  const size_t row0 = (size_t)by * 128;
  const int n0 = bx * 128;

  const int rbase0 = wv * 32, rbase1 = wv * 32 + 16;
  const int rA0 = rbase0 + (l >> 2), rA1 = rbase1 + (l >> 2);
  const int q0 = (l & 3) ^ ((rA0 >> 1) & 3), q1 = (l & 3) ^ ((rA1 >> 1) & 3);
  const unsigned short* gA0 = xh + (row0 + rA0) * 256 + q0 * 8;
  const unsigned short* gA1 = xh + (row0 + rA1) * 256 + q1 * 8;
  const unsigned short* gB0 = Wb + (size_t)(n0 + rA0) * 256 + q0 * 8;
  const unsigned short* gB1 = Wb + (size_t)(n0 + rA1) * 256 + q1 * 8;

  f32x4 acc[4][4] = {};

  auto stage = [&](int s, int d) {
    gl_lds16(gA0 + s * 32, &ldsb[d * 8192 + rbase0 * 64]);
    gl_lds16(gA1 + s * 32, &ldsb[d * 8192 + rbase1 * 64]);
    gl_lds16(gB0 + s * 32, &ldsb[16384 + d * 8192 + rbase0 * 64]);
    gl_lds16(gB1 + s * 32, &ldsb[16384 + d * 8192 + rbase1 * 64]);
  };

  stage(0, 0);
  __syncthreads();

  for (int s = 0; s < 8; ++s) {
    const int d = s & 1;
    if (s < 7) stage(s + 1, d ^ 1);
    half8 af[4], bf[4];
#pragma unroll
    for (int m = 0; m < 4; ++m) {
      const int r = wr * 64 + m * 16 + l15;
      af[m] = *(const half8*)&ldsb[d * 8192 + r * 64 + ((l4 ^ ((r >> 1) & 3)) * 16)];
    }
#pragma unroll
    for (int n = 0; n < 4; ++n) {
      const int r = wc * 64 + n * 16 + l15;
      bf[n] = *(const half8*)&ldsb[16384 + d * 8192 + r * 64 + ((l4 ^ ((r >> 1) & 3)) * 16)];
    }
#pragma unroll
    for (int n = 0; n < 4; ++n)
#pragma unroll
      for (int m = 0; m < 4; ++m)
        acc[m][n] = __builtin_amdgcn_mfma_f32_16x16x32_f16(af[m], bf[n], acc[m][n], 0, 0, 0);
    __syncthreads();
  }

  // Epilogue: C/D mapping col=lane&15, row=(lane>>4)*4+reg (m89-verified)
#pragma unroll
  for (int m = 0; m < 4; ++m)
#pragma unroll
    for (int n = 0; n < 4; ++n) {
      const int ng = n0 + wc * 64 + n * 16 + l15;
      unsigned short* op = qkv + (size_t)(ng >> 8) * 33554432 + (ng & 255);
#pragma unroll
      for (int r = 0; r < 4; ++r) {
        const size_t grow = row0 + wr * 64 + m * 16 + l4 * 4 + r;
        op[grow * 256] = f2h(acc[m][n][r]);
      }
    }
}

// ---------------- Kernel 2b: per-pixel relative-position projections ----------------
__global__ __launch_bounds__(256) void qrel(const unsigned short* __restrict__ q,
                                            const float* __restrict__ relx,
                                            const float* __restrict__ rely,
                                            unsigned short* __restrict__ qr) {
  __shared__ unsigned wpk[896];  // [0..447] x-pairs, [448..895] y-pairs; wpk[c2*7+j]
  for (int i = threadIdx.x; i < 896; i += 256) {
    const int hf = (i >= 448) ? 1 : 0;
    const int r = i - hf * 448;
    const int c2 = r / 7, j = r - c2 * 7;
    const float* R = hf ? rely : relx;
    wpk[i] = pk2h(R[(2 * c2) * 7 + j], R[(2 * c2 + 1) * 7 + j]);
  }
  __syncthreads();
  const size_t pix = (size_t)blockIdx.x * 256 + threadIdx.x;
  const uint4* qp = (const uint4*)(q + pix * 256);  // 32 uint4 = 256 fp16 channels
  float ax[7] = {0, 0, 0, 0, 0, 0, 0}, ay[7] = {0, 0, 0, 0, 0, 0, 0};
#pragma unroll
  for (int g = 0; g < 32; ++g) {
    const uint4 u = qp[g];
    const int c2b = (g & 15) * 4;
    if (g < 16) {
#pragma unroll
      for (int j = 0; j < 7; ++j) {
        float s = ax[j];
        s = dot2(h2cast(u.x), h2cast(wpk[(c2b + 0) * 7 + j]), s);
        s = dot2(h2cast(u.y), h2cast(wpk[(c2b + 1) * 7 + j]), s);
        s = dot2(h2cast(u.z), h2cast(wpk[(c2b + 2) * 7 + j]), s);
        s = dot2(h2cast(u.w), h2cast(wpk[(c2b + 3) * 7 + j]), s);
        ax[j] = s;
      }
    } else {
#pragma unroll
      for (int j = 0; j < 7; ++j) {
        float s = ay[j];
        s = dot2(h2cast(u.x), h2cast(wpk[448 + (c2b + 0) * 7 + j]), s);
        s = dot2(h2cast(u.y), h2cast(wpk[448 + (c2b + 1) * 7 + j]), s);
        s = dot2(h2cast(u.z), h2cast(wpk[448 + (c2b + 2) * 7 + j]), s);
        s = dot2(h2cast(u.w), h2cast(wpk[448 + (c2b + 3) * 7 + j]), s);
        ay[j] = s;
      }
    }
  }
  uint4 o0, o1;
  o0.x = pk2h(ax[0], ax[1]); o0.y = pk2h(ax[2], ax[3]);
  o0.z = pk2h(ax[4], ax[5]); o0.w = pk2h(ax[6], ay[0]);
  o1.x = pk2h(ay[1], ay[2]); o1.y = pk2h(ay[3], ay[4]);
  o1.z = pk2h(ay[5], ay[6]); o1.w = 0;
  uint4* dst = (uint4*)(qr + pix * 512);
  dst[0] = o0; dst[1] = o1;
}

// ---------------- Kernel 3: fused windowed attention ----------------
// v8: v7's MFMA phase A (numerics verified), register pressure fixed. v7 failed on
// occupancy: acc[4][7] = 112 AGPR + 136 VGPR > 256/wave -> 1 wave/SIMD (occ 11.3%),
// latency-exposed, 201us. Fix: 512-thread block (8 waves); each wave owns 32 queries
// (2 groups of 16) -> acc[2][7] = 56 AGPR; total regs ~170 <= 256 -> >=2 waves/SIMD
// (enforced via __launch_bounds__(512,2)). 8 waves/CU = v3's proven-throughput-bound
// wave count. Phase B: pixel split across 2 threads by plane-half (49 taps x 2 b128
// each) -> per-CU LDS traffic identical to v3 phase B, VALU/thread halves.
// Group geometry (from v7, verified): wave w: row-pair rp=w>>1, col-half ch16=(w&1)*16;
// group g cols ch16+8g..+7; K union per group = 8x14 halo cells = 7 MFMA tiles;
// halo slot = (2rp+ur)*38 + ch16 + 8g + uc. A-frag: lane q=l&15, ch k=(l>>4)*8 via
// per-lane global Q load. D: col=l&15 (key), row=(l>>4)*4+reg (query).
// P hand-off through LDS (aliases dead kv dbuf, stride 52 f32, ~2.6us conflicts ok);
// then relpos+softmax+phase B per thread, v3 numerics verbatim.
__global__ __launch_bounds__(512, 2) void attn(const unsigned short* __restrict__ qkv,
                                               const float* __restrict__ bias,
                                               const unsigned short* __restrict__ qrelb,
                                               float* __restrict__ out) {
  __shared__ unsigned short kv[2][4][4256];  // 2 buf x 4 planes x 532 slots*8 = 68096 B

  const int tid = threadIdx.x;               // 0..511
  const int px = tid & 255;                  // phase-B pixel within tile
  const int ph = tid >> 8;                   // phase-B plane-half (0: ch0-15, 1: ch16-31)
  const int col = px & 31, row = px >> 5;
  const int wv = tid >> 6;                   // wave 0..7
  const int lo = tid & 15, hi = (tid >> 4) & 3;
  const int rp = wv >> 1;                    // row-pair 0..3
  const int ch16 = (wv & 1) * 16;            // column-half base

  const int pid = blockIdx.x;
  const int cid = (pid & 7) * 64 + (pid >> 3);   // XCD-chunked (512 = 8*64, bijective)
  const int ht = cid & 15, wt = (cid >> 4) & 3, b = cid >> 6;

  const int h = ht * 8 + row, w = wt * 32 + col;
  const size_t pix = (size_t)((b * 128 + h) * 128 + w);
  const int pbase = row * 38 + col;              // phase-B thread's halo-pixel index

  const unsigned short* qb = qkv;
  const unsigned short* kb = qkv + 33554432;
  const unsigned short* vb = qkv + 67108864;

  // staging geometry: 532 halo slots; thread covers slot tid, and tid+512 (<532)
  const int pr0 = tid / 38, pc0 = tid - pr0 * 38;
  const int gh0 = ht * 8 + pr0 - 3, gw0 = wt * 32 + pc0 - 3;
  const bool ok0 = ((unsigned)gh0 < 128u) && ((unsigned)gw0 < 128u);
  const long long go0 = ((long long)((b * 128 + gh0) * 128 + gw0)) * 256;  // shorts

  const int p1 = tid + 512;
  const int pr1 = p1 / 38, pc1 = p1 - pr1 * 38;
  const int gh1 = ht * 8 + pr1 - 3, gw1 = wt * 32 + pc1 - 3;
  const bool ok1 = (p1 < 532) && ((unsigned)gh1 < 128u) && ((unsigned)gw1 < 128u);
  const long long go1 = ((long long)((b * 128 + gh1) * 128 + gw1)) * 256;

  // async stage of chunk c (4 planes) into buffer d (no registers, no waits)
  auto stage = [&](const unsigned short* base, int c, int d) {
#pragma unroll
    for (int g = 0; g < 4; ++g) {
      if (ok0) gl_lds16(base + go0 + c * 32 + g * 8, &kv[d][g][wv * 512]);
      if (ok1) gl_lds16(base + go1 + c * 32 + g * 8, &kv[d][g][4096]);
    }
  };

  // zero OOB halo slots (both buffers); needed before phase A and again before phase B
  auto zero_oob = [&]() {
    const uint4 z = make_uint4(0u, 0u, 0u, 0u);
    for (int p = tid; p < 532; p += 512) {
      const int pr = p / 38, pc = p - pr * 38;
      const int gh = ht * 8 + pr - 3, gw = wt * 32 + pc - 3;
      if (!((unsigned)gh < 128u && (unsigned)gw < 128u)) {
#pragma unroll
        for (int d = 0; d < 2; ++d)
#pragma unroll
          for (int g = 0; g < 4; ++g)
            *(uint4*)&kv[d][g][p * 8] = z;
      }
    }
  };

  zero_oob();
  stage(kb, 0, 0);
  __syncthreads();   // implicit vmcnt(0): chunk-0 K staged + OOB zeros visible

  // ---- Phase A (MFMA): acc[g][t] = S[16q][16keys of tile t], accumulated over chunks
  int slot0[7];
#pragma unroll
  for (int t = 0; t < 7; ++t) {
    const int p = t * 16 + lo;
    const int ur = p / 14, uc = p - ur * 14;
    slot0[t] = (2 * rp + ur) * 38 + ch16 + uc;
  }
  // lane's query pixel for g=0: (row 2rp + (lo>>3), col ch16 + (lo&7))
  const size_t qpix =
      (size_t)((b * 128 + ht * 8 + 2 * rp + (lo >> 3)) * 128 + wt * 32 + ch16 + (lo & 7));
  const unsigned short* qlane = qb + qpix * 256 + hi * 8;

  f32x4 acc[2][7] = {};

  for (int s = 0; s < 8; ++s) {
    const int d = s & 1;
    if (s < 7) stage(kb, s + 1, d ^ 1);
    half8 qf[2];
#pragma unroll
    for (int g = 0; g < 2; ++g)
      qf[g] = *(const half8*)(qlane + (size_t)g * 2048 + s * 32);  // +8 px per group
    const unsigned short* kpl = &kv[d][hi][0];
    __builtin_amdgcn_s_setprio(1);
#pragma unroll
    for (int t = 0; t < 7; ++t) {
      const unsigned short* kt = kpl + slot0[t] * 8;
#pragma unroll
      for (int g = 0; g < 2; ++g) {
        const half8 kf = *(const half8*)(kt + g * 64);
        acc[g][t] = __builtin_amdgcn_mfma_f32_16x16x32_f16(qf[g], kf, acc[g][t], 0, 0, 0);
      }
    }
    __builtin_amdgcn_s_setprio(0);
    __syncthreads();
  }

  // ---- P hand-off: scatter valid-window scores (f32) into P-buffer aliasing kv.
  // lane holds, per (t,r): query q=hi*4+r (D row), key p=16t+lo (D col). valid iff
  // di=ur-(q>>3), dj=uc-(q&7) in [0,7). P row = pixel index within tile.
  float* pbuf = (float*)&kv[0][0][0];  // 256 rows x 52 f32 = 53248 B <= 68096 B
#pragma unroll
  for (int t = 0; t < 7; ++t) {
    const int p = t * 16 + lo;
    const int ur = p / 14, uc = p - ur * 14;
#pragma unroll
    for (int r = 0; r < 4; ++r) {
      const int q = hi * 4 + r;
      const int di = ur - (q >> 3), dj = uc - (q & 7);
      if (((unsigned)di < 7u) && ((unsigned)dj < 7u)) {
        const int pslot = di * 7 + dj;
#pragma unroll
        for (int g = 0; g < 2; ++g) {
          const int prow_ = (2 * rp + (q >> 3)) * 32 + ch16 + 8 * g + (q & 7);
          pbuf[prow_ * 52 + pslot] = acc[g][t][r];
        }
      }
    }
  }
  __syncthreads();

  // each thread loads its pixel's 49 scores (tid and tid+256 read the same row)
  float sc[49];
  {
    const float* prow = pbuf + px * 52;
#pragma unroll
    for (int k = 0; k < 12; ++k) {
      const float4 v = ((const float4*)prow)[k];
      sc[k * 4 + 0] = v.x; sc[k * 4 + 1] = v.y;
      sc[k * 4 + 2] = v.z; sc[k * 4 + 3] = v.w;
    }
    sc[48] = prow[48];
  }
  __syncthreads();   // all P reads done before kv is clobbered below

  // restore kv for phase B: re-zero OOB slots, stage V chunk 0 into buf 0
  zero_oob();
  stage(vb, 0, 0);

  // qrel: 14 fp16 at this pixel's out-slot head (written by qrel; we overwrite later)
  float qx[7], qy[7];
  {
    const uint4* rpq = (const uint4*)(qrelb + pix * 512);
    uint4 r0 = rpq[0], r1 = rpq[1];
    half2v a0 = h2cast(r0.x), a1 = h2cast(r0.y), a2 = h2cast(r0.z), a3 = h2cast(r0.w);
    half2v b0 = h2cast(r1.x), b1 = h2cast(r1.y), b2 = h2cast(r1.z);
    qx[0] = a0[0]; qx[1] = a0[1]; qx[2] = a1[0]; qx[3] = a1[1];
    qx[4] = a2[0]; qx[5] = a2[1]; qx[6] = a3[0];
    qy[0] = a3[1]; qy[1] = b0[0]; qy[2] = b0[1]; qy[3] = b1[0];
    qy[4] = b1[1]; qy[5] = b2[0]; qy[6] = b2[1];
  }

  // ---- softmax over 49 (fp32, per thread; both plane-half threads redundantly) ----
#pragma unroll
  for (int i = 0; i < 7; ++i)
#pragma unroll
    for (int j = 0; j < 7; ++j) sc[i * 7 + j] += qx[j] + qy[i];
  float mx = sc[0];
#pragma unroll
  for (int t = 1; t < 49; ++t) mx = fmaxf(mx, sc[t]);
  float sum = 0.0f;
#pragma unroll
  for (int t = 0; t < 49; ++t) {
    float e = __expf(sc[t] - mx);
    sc[t] = e;
    sum += e;
  }
  const float invs = 1.0f / sum;
  unsigned pw[49];
#pragma unroll
  for (int t = 0; t < 49; ++t) {
    const unsigned short phv = f2h(sc[t] * invs);
    pw[t] = (unsigned)phv | ((unsigned)phv << 16);
  }
  __syncthreads();   // vmcnt(0): V chunk 0 + re-zeroed OOB visible

  // ---- Phase B: out = sum p*v + bias; thread handles planes {2ph, 2ph+1} of px ----
  for (int s = 0; s < 8; ++s) {
    const int d = s & 1;
    const int f0 = s * 32 + ph * 16;
    if (s < 7) stage(vb, s + 1, d ^ 1);
    half2v acc2[8];
#pragma unroll
    for (int a = 0; a < 8; ++a) acc2[a] = half2v{(_Float16)0, (_Float16)0};
    __builtin_amdgcn_s_setprio(1);
#pragma unroll
    for (int i = 0; i < 7; ++i)
#pragma unroll
      for (int j = 0; j < 7; ++j) {
        const int q8 = (pbase + i * 38 + j) * 8;
        uint4 v0 = *(const uint4*)&kv[d][2 * ph + 0][q8];
        uint4 v1 = *(const uint4*)&kv[d][2 * ph + 1][q8];
        const half2v p2h = h2cast(pw[i * 7 + j]);
        acc2[0] += p2h * h2cast(v0.x);  acc2[1] += p2h * h2cast(v0.y);
        acc2[2] += p2h * h2cast(v0.z);  acc2[3] += p2h * h2cast(v0.w);
        acc2[4] += p2h * h2cast(v1.x);  acc2[5] += p2h * h2cast(v1.y);
        acc2[6] += p2h * h2cast(v1.z);  acc2[7] += p2h * h2cast(v1.w);
      }
    __builtin_amdgcn_s_setprio(0);
#pragma unroll
    for (int fq = 0; fq < 4; ++fq) {
      float4 bv = *(const float4*)&bias[f0 + fq * 4];
      float4 o;
      o.x = (float)acc2[fq * 2 + 0][0] + bv.x;
      o.y = (float)acc2[fq * 2 + 0][1] + bv.y;
      o.z = (float)acc2[fq * 2 + 1][0] + bv.z;
      o.w = (float)acc2[fq * 2 + 1][1] + bv.w;
      *(float4*)&out[pix * 256 + f0 + fq * 4] = o;
    }
    if (s < 7) __syncthreads();
  }
}

extern "C" void kernel_launch(void* const* d_in, const int* in_sizes, int n_in,
                              void* d_out, int out_size, void* d_ws, size_t ws_size,
                              hipStream_t stream) {
  const float* x = (const float*)d_in[0];
  const float* Wq = (const float*)d_in[1];
  const float* Wk = (const float*)d_in[2];
  const float* Wv = (const float*)d_in[3];
  const float* relx = (const float*)d_in[4];
  const float* rely = (const float*)d_in[5];
  const float* bias = (const float*)d_in[6];
  float* out = (float*)d_out;

  // d_out doubles as scratch: xh (fp16 x) dead after qkv_gemm; qrel writes 32 B into each
  // pixel's out slot head, read by attn before that slot is overwritten.
  unsigned short* xh = (unsigned short*)d_out;
  unsigned short* qrl = (unsigned short*)d_out;
  // ws layout: Wb (fp16, 768*256 = 384 KB) | qkv (3 * 33554432 fp16 = 192 MB)
  unsigned short* Wb = (unsigned short*)d_ws;
  unsigned short* qkv = (unsigned short*)((char*)d_ws + 393216);

  xcvt<<<dim3(16384), dim3(256), 0, stream>>>(x, xh);
  wconv<<<dim3(768), dim3(256), 0, stream>>>(Wq, Wk, Wv, Wb);
  qkv_gemm<<<dim3(6144), dim3(256), 0, stream>>>(xh, Wb, qkv);
  qrel<<<dim3(512), dim3(256), 0, stream>>>(qkv, relx, rely, qrl);
  attn<<<dim3(512), dim3(512), 0, stream>>>(qkv, bias, qrl, out);
}

// Round 8
// 273.371 us; speedup vs baseline: 1.0988x; 1.0342x over previous
//
#include <hip/hip_runtime.h>
#include <hip/hip_fp16.h>
#include <stdint.h>

// Problem constants: B=8, H=W=128, C=F=256, K=7, PAD=3, rs=128
typedef _Float16 half8 __attribute__((ext_vector_type(8)));   // 8 fp16 = 4 VGPR (MFMA A/B frag)
typedef _Float16 half2v __attribute__((ext_vector_type(2)));  // packed fp16 pair
typedef __attribute__((ext_vector_type(4))) float f32x4;      // MFMA C/D frag

__device__ __forceinline__ unsigned short f2h(float f) {      // RNE fp32->fp16
  __half h = __float2half(f);
  unsigned short u; __builtin_memcpy(&u, &h, 2); return u;
}
__device__ __forceinline__ unsigned pk2h(float a, float b) {  // RTZ packed pair (staging only)
  auto v = __builtin_amdgcn_cvt_pkrtz(a, b);
  unsigned u; __builtin_memcpy(&u, &v, 4); return u;
}
__device__ __forceinline__ half2v h2cast(unsigned u) {
  half2v v; __builtin_memcpy(&v, &u, 4); return v;
}

#if __has_builtin(__builtin_amdgcn_fdot2)
__device__ __forceinline__ float dot2(half2v a, half2v b, float c) {
  return __builtin_amdgcn_fdot2(a, b, c, false);
}
#else
__device__ __forceinline__ float dot2(half2v a, half2v b, float c) {
  return c + (float)a[0] * (float)b[0] + (float)a[1] * (float)b[1];
}
#endif

// async global->LDS, 16B per lane; lds dest = wave-uniform base + lane*16
__device__ __forceinline__ void gl_lds16(const void* g, void* l) {
  __builtin_amdgcn_global_load_lds(
      (const __attribute__((address_space(1))) void*)g,
      (__attribute__((address_space(3))) void*)l, 16, 0, 0);
}

// ---------------- Kernel 0+1 merged: x fp32->fp16, and weight transpose+cvt ----------
// (one launch instead of two; bodies unchanged from the verified xcvt/wconv)
__global__ __launch_bounds__(256) void prep(const float* __restrict__ x,
                                            const float* __restrict__ Wq,
                                            const float* __restrict__ Wk,
                                            const float* __restrict__ Wv,
                                            unsigned short* __restrict__ xh,
                                            unsigned short* __restrict__ Wb) {
  const int bid = blockIdx.x;
  if (bid < 16384) {
    const size_t i = ((size_t)bid * 256 + threadIdx.x) * 8;
    float4 a = *(const float4*)&x[i];
    float4 b = *(const float4*)&x[i + 4];
    uint4 o;
    o.x = pk2h(a.x, a.y); o.y = pk2h(a.z, a.w);
    o.z = pk2h(b.x, b.y); o.w = pk2h(b.z, b.w);
    *(uint4*)&xh[i] = o;
  } else {
    const int e = bid - 16384;
    const int w = e >> 8;
    const int n = e & 255;
    const float* W = (w == 0) ? Wq : ((w == 1) ? Wk : Wv);
    const int k = threadIdx.x;
    Wb[(size_t)e * 256 + k] = f2h(W[(size_t)k * 256 + n]);
  }
}

// ---------------- Kernel 2: fused QKV GEMM (fp16 MFMA, global_load_lds staging) ----------
__global__ __launch_bounds__(256) void qkv_gemm(const unsigned short* __restrict__ xh,
                                                const unsigned short* __restrict__ Wb,
                                                unsigned short* __restrict__ qkv) {
  __shared__ unsigned char ldsb[32768];

  const int tid = threadIdx.x;
  const int l = tid & 63, l15 = l & 15, l4 = l >> 4;
  const int wv = tid >> 6, wr = wv >> 1, wc = wv & 1;

  // XCD-aware chunked swizzle: 6144 blocks, 8 XCDs, 768 per XCD (bijective).
  const int pid = blockIdx.x;
  const int cid = (pid & 7) * 768 + (pid >> 3);
  const int by = cid / 6;
  const int bx = cid - by * 6;
  const size_t row0 = (size_t)by * 128;
  const int n0 = bx * 128;

  const int rbase0 = wv * 32, rbase1 = wv * 32 + 16;
  const int rA0 = rbase0 + (l >> 2), rA1 = rbase1 + (l >> 2);
  const int q0 = (l & 3) ^ ((rA0 >> 1) & 3), q1 = (l & 3) ^ ((rA1 >> 1) & 3);
  const unsigned short* gA0 = xh + (row0 + rA0) * 256 + q0 * 8;
  const unsigned short* gA1 = xh + (row0 + rA1) * 256 + q1 * 8;
  const unsigned short* gB0 = Wb + (size_t)(n0 + rA0) * 256 + q0 * 8;
  const unsigned short* gB1 = Wb + (size_t)(n0 + rA1) * 256 + q1 * 8;

  f32x4 acc[4][4] = {};

  auto stage = [&](int s, int d) {
    gl_lds16(gA0 + s * 32, &ldsb[d * 8192 + rbase0 * 64]);
    gl_lds16(gA1 + s * 32, &ldsb[d * 8192 + rbase1 * 64]);
    gl_lds16(gB0 + s * 32, &ldsb[16384 + d * 8192 + rbase0 * 64]);
    gl_lds16(gB1 + s * 32, &ldsb[16384 + d * 8192 + rbase1 * 64]);
  };

  stage(0, 0);
  __syncthreads();

  for (int s = 0; s < 8; ++s) {
    const int d = s & 1;
    if (s < 7) stage(s + 1, d ^ 1);
    half8 af[4], bf[4];
#pragma unroll
    for (int m = 0; m < 4; ++m) {
      const int r = wr * 64 + m * 16 + l15;
      af[m] = *(const half8*)&ldsb[d * 8192 + r * 64 + ((l4 ^ ((r >> 1) & 3)) * 16)];
    }
#pragma unroll
    for (int n = 0; n < 4; ++n) {
      const int r = wc * 64 + n * 16 + l15;
      bf[n] = *(const half8*)&ldsb[16384 + d * 8192 + r * 64 + ((l4 ^ ((r >> 1) & 3)) * 16)];
    }
#pragma unroll
    for (int n = 0; n < 4; ++n)
#pragma unroll
      for (int m = 0; m < 4; ++m)
        acc[m][n] = __builtin_amdgcn_mfma_f32_16x16x32_f16(af[m], bf[n], acc[m][n], 0, 0, 0);
    __syncthreads();
  }

  // Epilogue: C/D mapping col=lane&15, row=(lane>>4)*4+reg (m89-verified)
#pragma unroll
  for (int m = 0; m < 4; ++m)
#pragma unroll
    for (int n = 0; n < 4; ++n) {
      const int ng = n0 + wc * 64 + n * 16 + l15;
      unsigned short* op = qkv + (size_t)(ng >> 8) * 33554432 + (ng & 255);
#pragma unroll
      for (int r = 0; r < 4; ++r) {
        const size_t grow = row0 + wr * 64 + m * 16 + l4 * 4 + r;
        op[grow * 256] = f2h(acc[m][n][r]);
      }
    }
}

// ---------------- Kernel 2b: per-pixel relative-position projections ----------------
__global__ __launch_bounds__(256) void qrel(const unsigned short* __restrict__ q,
                                            const float* __restrict__ relx,
                                            const float* __restrict__ rely,
                                            unsigned short* __restrict__ qr) {
  __shared__ unsigned wpk[896];  // [0..447] x-pairs, [448..895] y-pairs; wpk[c2*7+j]
  for (int i = threadIdx.x; i < 896; i += 256) {
    const int hf = (i >= 448) ? 1 : 0;
    const int r = i - hf * 448;
    const int c2 = r / 7, j = r - c2 * 7;
    const float* R = hf ? rely : relx;
    wpk[i] = pk2h(R[(2 * c2) * 7 + j], R[(2 * c2 + 1) * 7 + j]);
  }
  __syncthreads();
  const size_t pix = (size_t)blockIdx.x * 256 + threadIdx.x;
  const uint4* qp = (const uint4*)(q + pix * 256);  // 32 uint4 = 256 fp16 channels
  float ax[7] = {0, 0, 0, 0, 0, 0, 0}, ay[7] = {0, 0, 0, 0, 0, 0, 0};
#pragma unroll
  for (int g = 0; g < 32; ++g) {
    const uint4 u = qp[g];
    const int c2b = (g & 15) * 4;
    if (g < 16) {
#pragma unroll
      for (int j = 0; j < 7; ++j) {
        float s = ax[j];
        s = dot2(h2cast(u.x), h2cast(wpk[(c2b + 0) * 7 + j]), s);
        s = dot2(h2cast(u.y), h2cast(wpk[(c2b + 1) * 7 + j]), s);
        s = dot2(h2cast(u.z), h2cast(wpk[(c2b + 2) * 7 + j]), s);
        s = dot2(h2cast(u.w), h2cast(wpk[(c2b + 3) * 7 + j]), s);
        ax[j] = s;
      }
    } else {
#pragma unroll
      for (int j = 0; j < 7; ++j) {
        float s = ay[j];
        s = dot2(h2cast(u.x), h2cast(wpk[448 + (c2b + 0) * 7 + j]), s);
        s = dot2(h2cast(u.y), h2cast(wpk[448 + (c2b + 1) * 7 + j]), s);
        s = dot2(h2cast(u.z), h2cast(wpk[448 + (c2b + 2) * 7 + j]), s);
        s = dot2(h2cast(u.w), h2cast(wpk[448 + (c2b + 3) * 7 + j]), s);
        ay[j] = s;
      }
    }
  }
  uint4 o0, o1;
  o0.x = pk2h(ax[0], ax[1]); o0.y = pk2h(ax[2], ax[3]);
  o0.z = pk2h(ax[4], ax[5]); o0.w = pk2h(ax[6], ay[0]);
  o1.x = pk2h(ay[1], ay[2]); o1.y = pk2h(ay[3], ay[4]);
  o1.z = pk2h(ay[5], ay[6]); o1.w = 0;
  uint4* dst = (uint4*)(qr + pix * 512);
  dst[0] = o0; dst[1] = o1;
}

// ---------------- Kernel 3: fused windowed attention ----------------
// v9 = v8 (MFMA phase A, 512 thr, verified) + phase-B ds_read BATCHING.
// v8 post-mortem: all pipes idle (VALU 19%, LDS ~10us of pipe time, HBM 18%) ->
// ~85% dependency stall; prime suspect = ds_read->use latency (~120cyc, m117)
// exposed because phase B issued only 2 reads per tap before consuming.
// Fix: per window row, load 4 taps' worth (8 b128 in flight) then FMA, then 3 more.
// +32 VGPR only in phase B where the 56 acc-AGPRs are dead -> stays in the <=128
// reg tier (4 waves/SIMD). Everything else byte-identical to v8.
__global__ __launch_bounds__(512, 2) void attn(const unsigned short* __restrict__ qkv,
                                               const float* __restrict__ bias,
                                               const unsigned short* __restrict__ qrelb,
                                               float* __restrict__ out) {
  __shared__ unsigned short kv[2][4][4256];  // 2 buf x 4 planes x 532 slots*8 = 68096 B

  const int tid = threadIdx.x;               // 0..511
  const int px = tid & 255;                  // phase-B pixel within tile
  const int ph = tid >> 8;                   // phase-B plane-half (0: ch0-15, 1: ch16-31)
  const int col = px & 31, row = px >> 5;
  const int wv = tid >> 6;                   // wave 0..7
  const int lo = tid & 15, hi = (tid >> 4) & 3;
  const int rp = wv >> 1;                    // row-pair 0..3
  const int ch16 = (wv & 1) * 16;            // column-half base

  const int pid = blockIdx.x;
  const int cid = (pid & 7) * 64 + (pid >> 3);   // XCD-chunked (512 = 8*64, bijective)
  const int ht = cid & 15, wt = (cid >> 4) & 3, b = cid >> 6;

  const int h = ht * 8 + row, w = wt * 32 + col;
  const size_t pix = (size_t)((b * 128 + h) * 128 + w);
  const int pbase = row * 38 + col;              // phase-B thread's halo-pixel index

  const unsigned short* qb = qkv;
  const unsigned short* kb = qkv + 33554432;
  const unsigned short* vb = qkv + 67108864;

  // staging geometry: 532 halo slots; thread covers slot tid, and tid+512 (<532)
  const int pr0 = tid / 38, pc0 = tid - pr0 * 38;
  const int gh0 = ht * 8 + pr0 - 3, gw0 = wt * 32 + pc0 - 3;
  const bool ok0 = ((unsigned)gh0 < 128u) && ((unsigned)gw0 < 128u);
  const long long go0 = ((long long)((b * 128 + gh0) * 128 + gw0)) * 256;  // shorts

  const int p1 = tid + 512;
  const int pr1 = p1 / 38, pc1 = p1 - pr1 * 38;
  const int gh1 = ht * 8 + pr1 - 3, gw1 = wt * 32 + pc1 - 3;
  const bool ok1 = (p1 < 532) && ((unsigned)gh1 < 128u) && ((unsigned)gw1 < 128u);
  const long long go1 = ((long long)((b * 128 + gh1) * 128 + gw1)) * 256;

  // async stage of chunk c (4 planes) into buffer d (no registers, no waits)
  auto stage = [&](const unsigned short* base, int c, int d) {
#pragma unroll
    for (int g = 0; g < 4; ++g) {
      if (ok0) gl_lds16(base + go0 + c * 32 + g * 8, &kv[d][g][wv * 512]);
      if (ok1) gl_lds16(base + go1 + c * 32 + g * 8, &kv[d][g][4096]);
    }
  };

  // zero OOB halo slots (both buffers); needed before phase A and again before phase B
  auto zero_oob = [&]() {
    const uint4 z = make_uint4(0u, 0u, 0u, 0u);
    for (int p = tid; p < 532; p += 512) {
      const int pr = p / 38, pc = p - pr * 38;
      const int gh = ht * 8 + pr - 3, gw = wt * 32 + pc - 3;
      if (!((unsigned)gh < 128u && (unsigned)gw < 128u)) {
#pragma unroll
        for (int d = 0; d < 2; ++d)
#pragma unroll
          for (int g = 0; g < 4; ++g)
            *(uint4*)&kv[d][g][p * 8] = z;
      }
    }
  };

  zero_oob();
  stage(kb, 0, 0);
  __syncthreads();   // implicit vmcnt(0): chunk-0 K staged + OOB zeros visible

  // ---- Phase A (MFMA): acc[g][t] = S[16q][16keys of tile t], accumulated over chunks
  int slot0[7];
#pragma unroll
  for (int t = 0; t < 7; ++t) {
    const int p = t * 16 + lo;
    const int ur = p / 14, uc = p - ur * 14;
    slot0[t] = (2 * rp + ur) * 38 + ch16 + uc;
  }
  // lane's query pixel for g=0: (row 2rp + (lo>>3), col ch16 + (lo&7))
  const size_t qpix =
      (size_t)((b * 128 + ht * 8 + 2 * rp + (lo >> 3)) * 128 + wt * 32 + ch16 + (lo & 7));
  const unsigned short* qlane = qb + qpix * 256 + hi * 8;

  f32x4 acc[2][7] = {};

  for (int s = 0; s < 8; ++s) {
    const int d = s & 1;
    if (s < 7) stage(kb, s + 1, d ^ 1);
    half8 qf[2];
#pragma unroll
    for (int g = 0; g < 2; ++g)
      qf[g] = *(const half8*)(qlane + (size_t)g * 2048 + s * 32);  // +8 px per group
    const unsigned short* kpl = &kv[d][hi][0];
    __builtin_amdgcn_s_setprio(1);
#pragma unroll
    for (int t = 0; t < 7; ++t) {
      const unsigned short* kt = kpl + slot0[t] * 8;
#pragma unroll
      for (int g = 0; g < 2; ++g) {
        const half8 kf = *(const half8*)(kt + g * 64);
        acc[g][t] = __builtin_amdgcn_mfma_f32_16x16x32_f16(qf[g], kf, acc[g][t], 0, 0, 0);
      }
    }
    __builtin_amdgcn_s_setprio(0);
    __syncthreads();
  }

  // ---- P hand-off: scatter valid-window scores (f32) into P-buffer aliasing kv.
  float* pbuf = (float*)&kv[0][0][0];  // 256 rows x 52 f32 = 53248 B <= 68096 B
#pragma unroll
  for (int t = 0; t < 7; ++t) {
    const int p = t * 16 + lo;
    const int ur = p / 14, uc = p - ur * 14;
#pragma unroll
    for (int r = 0; r < 4; ++r) {
      const int q = hi * 4 + r;
      const int di = ur - (q >> 3), dj = uc - (q & 7);
      if (((unsigned)di < 7u) && ((unsigned)dj < 7u)) {
        const int pslot = di * 7 + dj;
#pragma unroll
        for (int g = 0; g < 2; ++g) {
          const int prow_ = (2 * rp + (q >> 3)) * 32 + ch16 + 8 * g + (q & 7);
          pbuf[prow_ * 52 + pslot] = acc[g][t][r];
        }
      }
    }
  }
  __syncthreads();

  // each thread loads its pixel's 49 scores (tid and tid+256 read the same row)
  float sc[49];
  {
    const float* prow = pbuf + px * 52;
#pragma unroll
    for (int k = 0; k < 12; ++k) {
      const float4 v = ((const float4*)prow)[k];
      sc[k * 4 + 0] = v.x; sc[k * 4 + 1] = v.y;
      sc[k * 4 + 2] = v.z; sc[k * 4 + 3] = v.w;
    }
    sc[48] = prow[48];
  }
  __syncthreads();   // all P reads done before kv is clobbered below

  // restore kv for phase B: re-zero OOB slots, stage V chunk 0 into buf 0
  zero_oob();
  stage(vb, 0, 0);

  // qrel: 14 fp16 at this pixel's out-slot head (written by qrel; we overwrite later)
  float qx[7], qy[7];
  {
    const uint4* rpq = (const uint4*)(qrelb + pix * 512);
    uint4 r0 = rpq[0], r1 = rpq[1];
    half2v a0 = h2cast(r0.x), a1 = h2cast(r0.y), a2 = h2cast(r0.z), a3 = h2cast(r0.w);
    half2v b0 = h2cast(r1.x), b1 = h2cast(r1.y), b2 = h2cast(r1.z);
    qx[0] = a0[0]; qx[1] = a0[1]; qx[2] = a1[0]; qx[3] = a1[1];
    qx[4] = a2[0]; qx[5] = a2[1]; qx[6] = a3[0];
    qy[0] = a3[1]; qy[1] = b0[0]; qy[2] = b0[1]; qy[3] = b1[0];
    qy[4] = b1[1]; qy[5] = b2[0]; qy[6] = b2[1];
  }

  // ---- softmax over 49 (fp32, per thread; both plane-half threads redundantly) ----
#pragma unroll
  for (int i = 0; i < 7; ++i)
#pragma unroll
    for (int j = 0; j < 7; ++j) sc[i * 7 + j] += qx[j] + qy[i];
  float mx = sc[0];
#pragma unroll
  for (int t = 1; t < 49; ++t) mx = fmaxf(mx, sc[t]);
  float sum = 0.0f;
#pragma unroll
  for (int t = 0; t < 49; ++t) {
    float e = __expf(sc[t] - mx);
    sc[t] = e;
    sum += e;
  }
  const float invs = 1.0f / sum;
  unsigned pw[49];
#pragma unroll
  for (int t = 0; t < 49; ++t) {
    const unsigned short phv = f2h(sc[t] * invs);
    pw[t] = (unsigned)phv | ((unsigned)phv << 16);
  }
  __syncthreads();   // vmcnt(0): V chunk 0 + re-zeroed OOB visible

  // ---- Phase B: out = sum p*v + bias; thread handles planes {2ph, 2ph+1} of px ----
  // v9: batched reads — 8 b128 in flight (4 taps), FMA, then 6 more (3 taps).
  for (int s = 0; s < 8; ++s) {
    const int d = s & 1;
    const int f0 = s * 32 + ph * 16;
    if (s < 7) stage(vb, s + 1, d ^ 1);
    half2v acc2[8];
#pragma unroll
    for (int a = 0; a < 8; ++a) acc2[a] = half2v{(_Float16)0, (_Float16)0};
    __builtin_amdgcn_s_setprio(1);
#pragma unroll
    for (int i = 0; i < 7; ++i) {
      const int rb8 = (pbase + i * 38) * 8;
      uint4 ua[8];
#pragma unroll
      for (int j = 0; j < 4; ++j) {
        ua[2 * j + 0] = *(const uint4*)&kv[d][2 * ph + 0][rb8 + j * 8];
        ua[2 * j + 1] = *(const uint4*)&kv[d][2 * ph + 1][rb8 + j * 8];
      }
#pragma unroll
      for (int j = 0; j < 4; ++j) {
        const half2v p2h = h2cast(pw[i * 7 + j]);
        acc2[0] += p2h * h2cast(ua[2 * j + 0].x);  acc2[1] += p2h * h2cast(ua[2 * j + 0].y);
        acc2[2] += p2h * h2cast(ua[2 * j + 0].z);  acc2[3] += p2h * h2cast(ua[2 * j + 0].w);
        acc2[4] += p2h * h2cast(ua[2 * j + 1].x);  acc2[5] += p2h * h2cast(ua[2 * j + 1].y);
        acc2[6] += p2h * h2cast(ua[2 * j + 1].z);  acc2[7] += p2h * h2cast(ua[2 * j + 1].w);
      }
      uint4 ub[6];
#pragma unroll
      for (int j = 0; j < 3; ++j) {
        ub[2 * j + 0] = *(const uint4*)&kv[d][2 * ph + 0][rb8 + (j + 4) * 8];
        ub[2 * j + 1] = *(const uint4*)&kv[d][2 * ph + 1][rb8 + (j + 4) * 8];
      }
#pragma unroll
      for (int j = 0; j < 3; ++j) {
        const half2v p2h = h2cast(pw[i * 7 + 4 + j]);
        acc2[0] += p2h * h2cast(ub[2 * j + 0].x);  acc2[1] += p2h * h2cast(ub[2 * j + 0].y);
        acc2[2] += p2h * h2cast(ub[2 * j + 0].z);  acc2[3] += p2h * h2cast(ub[2 * j + 0].w);
        acc2[4] += p2h * h2cast(ub[2 * j + 1].x);  acc2[5] += p2h * h2cast(ub[2 * j + 1].y);
        acc2[6] += p2h * h2cast(ub[2 * j + 1].z);  acc2[7] += p2h * h2cast(ub[2 * j + 1].w);
      }
    }
    __builtin_amdgcn_s_setprio(0);
#pragma unroll
    for (int fq = 0; fq < 4; ++fq) {
      float4 bv = *(const float4*)&bias[f0 + fq * 4];
      float4 o;
      o.x = (float)acc2[fq * 2 + 0][0] + bv.x;
      o.y = (float)acc2[fq * 2 + 0][1] + bv.y;
      o.z = (float)acc2[fq * 2 + 1][0] + bv.z;
      o.w = (float)acc2[fq * 2 + 1][1] + bv.w;
      *(float4*)&out[pix * 256 + f0 + fq * 4] = o;
    }
    if (s < 7) __syncthreads();
  }
}

extern "C" void kernel_launch(void* const* d_in, const int* in_sizes, int n_in,
                              void* d_out, int out_size, void* d_ws, size_t ws_size,
                              hipStream_t stream) {
  const float* x = (const float*)d_in[0];
  const float* Wq = (const float*)d_in[1];
  const float* Wk = (const float*)d_in[2];
  const float* Wv = (const float*)d_in[3];
  const float* relx = (const float*)d_in[4];
  const float* rely = (const float*)d_in[5];
  const float* bias = (const float*)d_in[6];
  float* out = (float*)d_out;

  // d_out doubles as scratch: xh (fp16 x) dead after qkv_gemm; qrel writes 32 B into each
  // pixel's out slot head, read by attn before that slot is overwritten.
  unsigned short* xh = (unsigned short*)d_out;
  unsigned short* qrl = (unsigned short*)d_out;
  // ws layout: Wb (fp16, 768*256 = 384 KB) | qkv (3 * 33554432 fp16 = 192 MB)
  unsigned short* Wb = (unsigned short*)d_ws;
  unsigned short* qkv = (unsigned short*)((char*)d_ws + 393216);

  prep<<<dim3(17152), dim3(256), 0, stream>>>(x, Wq, Wk, Wv, xh, Wb);
  qkv_gemm<<<dim3(6144), dim3(256), 0, stream>>>(xh, Wb, qkv);
  qrel<<<dim3(512), dim3(256), 0, stream>>>(qkv, relx, rely, qrl);
  attn<<<dim3(512), dim3(512), 0, stream>>>(qkv, bias, qrl, out);
}